// Round 9
// baseline (66930.267 us; speedup 1.0000x reference)
//
#include <hip/hip_runtime.h>
#include <float.h>

constexpr int SEQ  = 128;   // sentence length T
constexpr int D    = 256;   // DIM / STATEDIM
constexpr int G    = 1024;  // 4*DIM gate width
constexpr int NREL = 26;    // REL_COUNT + 1
constexpr int NENT = 7;

typedef float v2f __attribute__((ext_vector_type(2)));

// ---------------------------------------------------------------------------
// Generic strided transpose: out[k*rows + i] = in[i*in_stride + in_off + k]
// ---------------------------------------------------------------------------
__global__ void k_trans(const float* __restrict__ in, float* __restrict__ out,
                        int rows, int cols, int in_stride, int in_off)
{
    int idx = blockIdx.x * 256 + threadIdx.x;
    if (idx >= rows * cols) return;
    int i = idx % rows;
    int k = idx / rows;
    out[idx] = in[(size_t)i * in_stride + in_off + k];
}

// ---------------------------------------------------------------------------
// xg[t][j] = bih[j] + bhh[j] + sum_k wordvector[text[t]][k] * Wih[j][k]
// ---------------------------------------------------------------------------
__global__ __launch_bounds__(1024) void k_xg(
    const int* __restrict__ text, const float* __restrict__ wv,
    const float* __restrict__ Wih, const float* __restrict__ bih,
    const float* __restrict__ bhh, float* __restrict__ xg)
{
    int t = blockIdx.x, j = threadIdx.x;
    const float* x  = wv + (size_t)text[t] * D;
    const float* wr = Wih + (size_t)j * D;
    float acc = bih[j] + bhh[j];
    for (int k = 0; k < D; ++k) acc += x[k] * wr[k];
    xg[t * G + j] = acc;
}

// ---------------------------------------------------------------------------
// Sequential LSTM, one block per direction (grid=2), 1024 threads.
// ---------------------------------------------------------------------------
__global__ __launch_bounds__(1024) void k_lstm(
    const float* __restrict__ xgF, const float* __restrict__ xgB,
    const float* __restrict__ WHTF, const float* __restrict__ WHTB,
    float* __restrict__ wordin)
{
    int dir = blockIdx.x;
    const float* xg  = dir ? xgB  : xgF;
    const float* WHT = dir ? WHTB : WHTF;
    __shared__ float h[D], c[D], g[G];
    int j = threadIdx.x;
    if (j < D) { h[j] = 0.f; c[j] = 0.f; }
    __syncthreads();
    for (int s = 0; s < SEQ; ++s) {
        int t = dir ? (SEQ - 1 - s) : s;
        float acc = xg[t * G + j];
        for (int k = 0; k < D; ++k) acc += WHT[k * G + j] * h[k];
        g[j] = acc;
        __syncthreads();
        if (j < D) {
            float si = 1.f / (1.f + expf(-g[j]));
            float sf = 1.f / (1.f + expf(-g[D + j]));
            float gg = tanhf(g[2 * D + j]);
            float so = 1.f / (1.f + expf(-g[3 * D + j]));
            float cn = sf * c[j] + si * gg;
            float hn = so * tanhf(cn);
            c[j] = cn; h[j] = hn;
            wordin[t * (2 * D) + dir * D + j] = hn;
        }
        __syncthreads();
    }
}

// ---------------------------------------------------------------------------
// Parallel precompute after LSTM (TW/BW per word, RV per relation, EV per ent)
// ---------------------------------------------------------------------------
__global__ __launch_bounds__(256) void k_prep2(
    const float* __restrict__ wordin,
    const float* __restrict__ WTWT, const float* __restrict__ WBWT,
    const float* __restrict__ WTRT, const float* __restrict__ WBET,
    const float* __restrict__ relvec, const float* __restrict__ entvec,
    const float* __restrict__ btv, const float* __restrict__ bbv,
    float* __restrict__ TW, float* __restrict__ BW,
    float* __restrict__ RV, float* __restrict__ EV)
{
    int b = blockIdx.x, i = threadIdx.x;
    if (b < SEQ) {
        const float* w = wordin + b * (2 * D);
        float a1 = btv[i], a2 = bbv[i];
        for (int j = 0; j < 2 * D; ++j) {
            float wv = w[j];
            a1 += wv * WTWT[j * D + i];
            a2 += wv * WBWT[j * D + i];
        }
        TW[b * D + i] = a1;
        BW[b * D + i] = a2;
    } else if (b < SEQ + NREL) {
        int r = b - SEQ;
        const float* x = relvec + r * D;
        float a = 0.f;
        for (int k = 0; k < D; ++k) a += x[k] * WTRT[k * D + i];
        RV[r * D + i] = a;
    } else {
        int e = b - SEQ - NREL;
        const float* x = entvec + e * D;
        float a = 0.f;
        for (int k = 0; k < D; ++k) a += x[k] * WBET[k * D + i];
        EV[e * D + i] = a;
    }
}

// ---------------------------------------------------------------------------
// M1T[j*D + i] = sum_k WBGT[k*D+i] * Wtt[k*D+j]   (M1 = Wb_target @ Wtt)
// ---------------------------------------------------------------------------
__global__ __launch_bounds__(256) void k_m1(
    const float* __restrict__ WBGT, const float* __restrict__ Wtt,
    float* __restrict__ M1T)
{
    int j = blockIdx.x, i = threadIdx.x;
    float a = 0.f;
    for (int k = 0; k < D; ++k) a = fmaf(WBGT[k * D + i], Wtt[k * D + j], a);
    M1T[j * D + i] = a;
}

// c1[i] = sum_k WBGT[k*D+i] * btt[k]
__global__ __launch_bounds__(256) void k_c1(
    const float* __restrict__ WBGT, const float* __restrict__ btt,
    float* __restrict__ c1)
{
    int i = threadIdx.x;
    float a = 0.f;
    for (int k = 0; k < D; ++k) a = fmaf(WBGT[k * D + i], btt[k], a);
    c1[i] = a;
}

// ---------------------------------------------------------------------------
// Packs for the 3-tier bot weight matvec (256 threads, thread i = output i):
//  reg tier   k=0..127 : WREG[i*128 + q]            = Wb[i][768 + q]
//  LDS tier   k=128..223: f4 slot (w*24+j)*64+l      = Wb[w*64+l][896 + 4j+c]
//  L2 tier    k=224..255: f4 slot j*256 + i          = Wb[i][992 + 4j+c]
// ---------------------------------------------------------------------------
__global__ __launch_bounds__(256) void k_pack8r(
    const float* __restrict__ Wb, float* __restrict__ WREG)
{
    int e = blockIdx.x * 256 + threadIdx.x;      // 0..32767
    int i = e >> 7, q = e & 127;
    WREG[e] = Wb[(size_t)i * (5 * D) + 3 * D + q];
}

__global__ __launch_bounds__(256) void k_pack8l(
    const float* __restrict__ Wb, float* __restrict__ WLDS)
{
    int f = blockIdx.x * 256 + threadIdx.x;      // 0..24575
    int f4 = f >> 2, c = f & 3;
    int l = f4 & 63, rest = f4 >> 6;
    int j = rest % 24, w = rest / 24;
    WLDS[f] = Wb[(size_t)(w * 64 + l) * (5 * D) + 3 * D + 128 + 4 * j + c];
}

__global__ __launch_bounds__(256) void k_pack8g(
    const float* __restrict__ Wb, float* __restrict__ WGL)
{
    int f = blockIdx.x * 256 + threadIdx.x;      // 0..8191
    int f4 = f >> 2, c = f & 3;
    int i = f4 & 255, j = f4 >> 8;
    WGL[f] = Wb[(size_t)i * (5 * D) + 3 * D + 224 + 4 * j + c];
}

// ---------------------------------------------------------------------------
// Full-k streamed matvec (top steps): Wcol = W^T[.. *D + i] (k-major, L2),
// x4 = LDS vector as float4 (broadcast reads). 4 independent chains.
// ---------------------------------------------------------------------------
__device__ inline float mv_full(const float* __restrict__ Wcol,
                                const float4* __restrict__ x4)
{
    float a0 = 0.f, a1 = 0.f, a2 = 0.f, a3 = 0.f;
    #pragma unroll 8
    for (int kk = 0; kk < 64; ++kk) {
        float4 xv = x4[kk];
        a0 = fmaf(Wcol[(4 * kk + 0) * D], xv.x, a0);
        a1 = fmaf(Wcol[(4 * kk + 1) * D], xv.y, a1);
        a2 = fmaf(Wcol[(4 * kk + 2) * D], xv.z, a2);
        a3 = fmaf(Wcol[(4 * kk + 3) * D], xv.w, a3);
    }
    return (a0 + a1) + (a2 + a3);
}

// ---------------------------------------------------------------------------
// Softmax + first-occurrence argmax over n values in lanes 0..n-1 of each
// W-lane group (reference-faithful: p = exp(l-max)/sum, argmax over p).
// ---------------------------------------------------------------------------
template<int W>
__device__ inline void grp_smax(float lv, int n, int lane, int& am, float& pm)
{
    float mx = lv;
    #pragma unroll
    for (int off = W / 2; off; off >>= 1) mx = fmaxf(mx, __shfl_xor(mx, off));
    float e  = (lane < n) ? expf(lv - mx) : 0.f;
    float se = e;
    #pragma unroll
    for (int off = W / 2; off; off >>= 1) se += __shfl_xor(se, off);
    float p  = (lane < n) ? (e / se) : -1.f;
    float q  = p;
    #pragma unroll
    for (int off = W / 2; off; off >>= 1) q = fmaxf(q, __shfl_xor(q, off));
    unsigned long long mask = __ballot(p == q);
    am = __ffsll((long long)mask) - 1;
    pm = q;
}

// FMA helpers: one float4 pair into two v2f accumulators
#define FMA_AB(Wv, Xv)                                                        \
    { float4 xx_ = (Xv);                                                      \
      A0 = __builtin_elementwise_fma((v2f){(Wv).x, (Wv).y},                   \
                                     (v2f){xx_.x, xx_.y}, A0);                \
      A1 = __builtin_elementwise_fma((v2f){(Wv).z, (Wv).w},                   \
                                     (v2f){xx_.z, xx_.w}, A1); }
#define FMA_CD(Wv, Xv)                                                        \
    { float4 xx_ = (Xv);                                                      \
      A2 = __builtin_elementwise_fma((v2f){(Wv).x, (Wv).y},                   \
                                     (v2f){xx_.x, xx_.y}, A2);                \
      A3 = __builtin_elementwise_fma((v2f){(Wv).z, (Wv).w},                   \
                                     (v2f){xx_.z, xx_.w}, A3); }

// ---------------------------------------------------------------------------
// Sequential main kernel: 1 block, 256 threads = 4 waves = 1 wave/SIMD.
// Why 256 threads: the allocator's empirical cap is 65536/blockSize VGPRs
// (R1-R8), so 256 threads is the only config granting 256 regs/thread.
// Thread i owns output column i. Weight tiers: 128 floats in 32 NAMED f4
// registers, 96 floats in LDS (conflict-free wave-contiguous layout), 32
// floats re-streamed from L2 every step (asm-pinned pointer so LICM cannot
// turn them into spillable long-lived registers). sched_barrier(0) fences
// cap the scheduler's load-hoisting (R8 failure: ~196 hoisted transient regs
// blew the budget and the weights spilled -> 1.8 GB/dispatch scratch writes).
// One __syncthreads per bot step (lpartB double-buffered, xbuf ping-pong).
// ---------------------------------------------------------------------------
__global__ __launch_bounds__(256)
void k_main7(
    const float* __restrict__ TW,   const float* __restrict__ BW,
    const float* __restrict__ RV,   const float* __restrict__ EV,
    const float* __restrict__ WTMT, const float* __restrict__ WTBT,
    const float* __restrict__ WBTT, const float* __restrict__ M1T,
    const float* __restrict__ c1v,  const float* __restrict__ WREG,
    const float* __restrict__ WLDS, const float* __restrict__ WGL,
    const float* __restrict__ Wp,   const float* __restrict__ bp,
    const float* __restrict__ Wpl,  const float* __restrict__ bpl,
    const float* __restrict__ btb,  const float* __restrict__ bbt,
    float* __restrict__ out)
{
    const int tid  = threadIdx.x;     // = output index i
    const int lane = tid & 63;
    const int w8   = tid >> 6;        // wave id 0..3

    __shared__ __align__(16) float wlds[256 * 96];     // 96 KB weight tier
    __shared__ __align__(16) float xbuf[2][D];
    __shared__ __align__(16) float mem[D], outv[D];
    __shared__ __align__(16) float Esh[NENT * D], WrSh[NENT * D];
    __shared__ float lpartT[4][32];
    __shared__ float lpartB[2][4][8];
    __shared__ float brSh[8];

    // stage LDS weight tier (pre-packed in exact LDS layout)
    {
        const float4* g4 = reinterpret_cast<const float4*>(WLDS);
        float4* w4 = reinterpret_cast<float4*>(wlds);
        #pragma unroll
        for (int it = 0; it < 24; ++it) w4[tid + it * 256] = g4[tid + it * 256];
    }
    for (int k = tid; k < NENT * D; k += 256) Esh[k] = EV[k];
    mem[tid] = 0.f;

    // register tier: 32 NAMED float4 (128 VGPRs), loaded once
    const float4* r4 = reinterpret_cast<const float4*>(WREG) + tid * 32;
    float4 wr0 = r4[0],   wr1 = r4[1],   wr2 = r4[2],   wr3 = r4[3];
    float4 wr4 = r4[4],   wr5 = r4[5],   wr6 = r4[6],   wr7 = r4[7];
    float4 wr8 = r4[8],   wr9 = r4[9],   wr10 = r4[10], wr11 = r4[11];
    float4 wr12 = r4[12], wr13 = r4[13], wr14 = r4[14], wr15 = r4[15];
    float4 wr16 = r4[16], wr17 = r4[17], wr18 = r4[18], wr19 = r4[19];
    float4 wr20 = r4[20], wr21 = r4[21], wr22 = r4[22], wr23 = r4[23];
    float4 wr24 = r4[24], wr25 = r4[25], wr26 = r4[26], wr27 = r4[27];
    float4 wr28 = r4[28], wr29 = r4[29], wr30 = r4[30], wr31 = r4[31];

    __syncthreads();

    const float4* wbase =
        reinterpret_cast<const float4*>(wlds) + (size_t)w8 * (24 * 64) + lane;
    const float4* gl = reinterpret_cast<const float4*>(WGL) + tid;

    const float* WTMc = WTMT + tid;
    const float* WTBc = WTBT + tid;
    const float* WBTc = WBTT + tid;
    const float* M1c  = M1T  + tid;

    int rel = 0;

    for (int t = 0; t < SEQ; ++t) {
        // ---- top step: outp = tanh(TW[t] + RV[rel] + Wt_m @ mem) ----
        float a = mv_full(WTMc, reinterpret_cast<const float4*>(mem));
        float outp = tanhf(a + TW[t * D + tid] + RV[rel * D + tid]);
        outv[tid] = outp;
        for (int r = 0; r < NREL; ++r) {
            float pp = outp * Wp[r * D + tid];
            #pragma unroll
            for (int off = 32; off; off >>= 1) pp += __shfl_xor(pp, off);
            if (lane == 0) lpartT[w8][r] = pp;
        }
        __syncthreads();
        float lv = -FLT_MAX;
        if (lane < NREL)
            lv = lpartT[0][lane] + lpartT[1][lane] + lpartT[2][lane] +
                 lpartT[3][lane] + bp[lane];
        int am; float pm;
        grp_smax<32>(lv, NREL, lane, am, pm);
        if (tid == 0) { out[t] = (float)am; out[SEQ + t] = pm; }
        const int action = am;   // wave-uniform

        if (action > 0) {
            rel = action;
            // memb0 = Wtb@outp + btb ;  btm = M1@outp + c1  (tgt folded away)
            float bs = mv_full(WTBc, reinterpret_cast<const float4*>(outv));
            float cs = mv_full(M1c,  reinterpret_cast<const float4*>(outv));
            const size_t wb0 = (size_t)(action - 1) * NENT * D;
            for (int k = tid; k < NENT * D; k += 256) WrSh[k] = Wpl[wb0 + k];
            if (tid < NENT) brSh[tid] = bpl[(action - 1) * NENT + tid];
            float btm = cs + c1v[tid];
            xbuf[0][tid] = bs + btb[tid];
            float bwc = BW[tid];            // prefetch BW row 0
            __syncthreads();

            int p = 0, ab = 0;
            for (int s = 0; s < SEQ; ++s) {
                const float4* xb = reinterpret_cast<const float4*>(xbuf[p]);
                // L2 tier: force per-step reload (pin pointer against LICM)
                const float4* glv = gl;
                asm volatile("" : "+v"(glv));
                float4 g0 = glv[0 * 256], g1 = glv[1 * 256],
                       g2 = glv[2 * 256], g3 = glv[3 * 256],
                       g4 = glv[4 * 256], g5 = glv[5 * 256],
                       g6 = glv[6 * 256], g7 = glv[7 * 256];

                v2f A0 = {0.f, 0.f}, A1 = {0.f, 0.f},
                    A2 = {0.f, 0.f}, A3 = {0.f, 0.f};
                // reg tier k=0..127 (fenced in halves to cap live xb loads)
                FMA_AB(wr0,  xb[0])  FMA_CD(wr1,  xb[1])
                FMA_AB(wr2,  xb[2])  FMA_CD(wr3,  xb[3])
                FMA_AB(wr4,  xb[4])  FMA_CD(wr5,  xb[5])
                FMA_AB(wr6,  xb[6])  FMA_CD(wr7,  xb[7])
                FMA_AB(wr8,  xb[8])  FMA_CD(wr9,  xb[9])
                FMA_AB(wr10, xb[10]) FMA_CD(wr11, xb[11])
                FMA_AB(wr12, xb[12]) FMA_CD(wr13, xb[13])
                FMA_AB(wr14, xb[14]) FMA_CD(wr15, xb[15])
                __builtin_amdgcn_sched_barrier(0);
                FMA_AB(wr16, xb[16]) FMA_CD(wr17, xb[17])
                FMA_AB(wr18, xb[18]) FMA_CD(wr19, xb[19])
                FMA_AB(wr20, xb[20]) FMA_CD(wr21, xb[21])
                FMA_AB(wr22, xb[22]) FMA_CD(wr23, xb[23])
                FMA_AB(wr24, xb[24]) FMA_CD(wr25, xb[25])
                FMA_AB(wr26, xb[26]) FMA_CD(wr27, xb[27])
                FMA_AB(wr28, xb[28]) FMA_CD(wr29, xb[29])
                FMA_AB(wr30, xb[30]) FMA_CD(wr31, xb[31])
                __builtin_amdgcn_sched_barrier(0);
                // LDS tier k=128..223, 8 f4 per fenced chunk
                #pragma unroll
                for (int j = 0; j < 24; j += 8) {
                    float4 wa = wbase[(j + 0) * 64], wb_ = wbase[(j + 1) * 64];
                    float4 wc = wbase[(j + 2) * 64], wd  = wbase[(j + 3) * 64];
                    float4 we = wbase[(j + 4) * 64], wf  = wbase[(j + 5) * 64];
                    float4 wg = wbase[(j + 6) * 64], wh  = wbase[(j + 7) * 64];
                    FMA_AB(wa, xb[32 + j + 0]) FMA_CD(wb_, xb[32 + j + 1])
                    FMA_AB(wc, xb[32 + j + 2]) FMA_CD(wd,  xb[32 + j + 3])
                    FMA_AB(we, xb[32 + j + 4]) FMA_CD(wf,  xb[32 + j + 5])
                    FMA_AB(wg, xb[32 + j + 6]) FMA_CD(wh,  xb[32 + j + 7])
                    __builtin_amdgcn_sched_barrier(0);
                }
                // L2 tier k=224..255
                FMA_AB(g0, xb[56]) FMA_CD(g1, xb[57])
                FMA_AB(g2, xb[58]) FMA_CD(g3, xb[59])
                FMA_AB(g4, xb[60]) FMA_CD(g5, xb[61])
                FMA_AB(g6, xb[62]) FMA_CD(g7, xb[63])
                v2f AS = (A0 + A1) + (A2 + A3);
                float ms = AS.x + AS.y;

                float ob = tanhf(ms + bwc + Esh[ab * D + tid] + btm);
                xbuf[p ^ 1][tid] = ob;
                #pragma unroll
                for (int r = 0; r < NENT; ++r) {
                    float pp = ob * WrSh[r * D + tid];
                    #pragma unroll
                    for (int off = 32; off; off >>= 1)
                        pp += __shfl_xor(pp, off);
                    if (lane == 0) lpartB[p][w8][r] = pp;
                }
                __syncthreads();                      // the ONE barrier/step
                float lv2 = -FLT_MAX;
                if (lane < NENT)
                    lv2 = lpartB[p][0][lane] + lpartB[p][1][lane] +
                          lpartB[p][2][lane] + lpartB[p][3][lane] + brSh[lane];
                int am2; float pm2;
                grp_smax<8>(lv2, NENT, lane, am2, pm2);
                if (tid == 0) {
                    out[2 * SEQ + t * SEQ + s] = (float)am2;
                    out[2 * SEQ + SEQ * SEQ + t * SEQ + s] = pm2;
                }
                ab = am2;
                int sn = (s + 1 < SEQ) ? s + 1 : s;
                bwc = BW[sn * D + tid];               // prefetch next row
                p ^= 1;
            }
            // mem = Wbt @ membf + bbt
            float es = mv_full(WBTc, reinterpret_cast<const float4*>(xbuf[p]));
            mem[tid] = es + bbt[tid];
            __syncthreads();
        } else {
            mem[tid] = outp;
            if (tid < SEQ) {
                out[2 * SEQ + t * SEQ + tid] = 0.f;
                out[2 * SEQ + SEQ * SEQ + t * SEQ + tid] = 0.f;
            }
            __syncthreads();
        }
    }
}

// ---------------------------------------------------------------------------
extern "C" void kernel_launch(void* const* d_in, const int* in_sizes, int n_in,
                              void* d_out, int out_size, void* d_ws, size_t ws_size,
                              hipStream_t stream)
{
    (void)in_sizes; (void)n_in; (void)out_size; (void)ws_size;
    const int*   text       = (const int*)  d_in[0];
    const float* wordvector = (const float*)d_in[1];
    const float* relvec     = (const float*)d_in[2];
    const float* entvec     = (const float*)d_in[3];
    const float* WihL = (const float*)d_in[4];  const float* WhhL = (const float*)d_in[5];
    const float* bihL = (const float*)d_in[6];  const float* bhhL = (const float*)d_in[7];
    const float* WihR = (const float*)d_in[8];  const float* WhhR = (const float*)d_in[9];
    const float* bihR = (const float*)d_in[10]; const float* bhhR = (const float*)d_in[11];
    const float* Wt   = (const float*)d_in[12]; const float* bt   = (const float*)d_in[13];
    const float* Wp   = (const float*)d_in[14]; const float* bp   = (const float*)d_in[15];
    const float* Wb   = (const float*)d_in[16]; const float* bb   = (const float*)d_in[17];
    const float* Wpl  = (const float*)d_in[18]; const float* bpl  = (const float*)d_in[19];
    const float* Wtt  = (const float*)d_in[20]; const float* btt  = (const float*)d_in[21];
    const float* Wtb  = (const float*)d_in[22]; const float* btb  = (const float*)d_in[23];
    const float* Wbt  = (const float*)d_in[24]; const float* bbt  = (const float*)d_in[25];

    float* ws = (float*)d_ws;
    size_t o = 0;
    auto take = [&](size_t n) { float* p = ws + o; o += n; return p; };
    float* XGF    = take(SEQ * G);
    float* XGB    = take(SEQ * G);
    float* WHLT   = take(D * G);
    float* WHRT   = take(D * G);
    float* WORDIN = take(SEQ * 2 * D);
    float* TW     = take(SEQ * D);
    float* BW     = take(SEQ * D);
    float* RVb    = take(NREL * D);
    float* EVb    = take(NENT * D);
    float* WTWT   = take(2 * D * D);
    float* WTRT   = take(D * D);
    float* WTMT   = take(D * D);
    float* WBWT   = take(2 * D * D);
    float* WBET   = take(D * D);
    float* WBGT   = take(D * D);
    float* WTBT   = take(D * D);
    float* WBTT   = take(D * D);
    float* M1T    = take(D * D);
    float* C1     = take(D);
    float* WREG   = take(256 * 128);     // register-tier pack (k 0..127)
    float* WLDS   = take(256 * 96);      // LDS-tier pack (k 128..223)
    float* WGL    = take(256 * 32);      // L2-tier pack (k 224..255)

    auto tr = [&](const float* in, float* outp, int rows, int cols, int stride, int off) {
        int n = rows * cols;
        k_trans<<<(n + 255) / 256, 256, 0, stream>>>(in, outp, rows, cols, stride, off);
    };
    tr(WhhL, WHLT, G, D, D, 0);          // WHLT[k*G + j] = WhhL[j][k]
    tr(WhhR, WHRT, G, D, D, 0);
    tr(Wt,  WTWT, D, 2 * D, G, 0);       // word part of Wt
    tr(Wt,  WTRT, D, D, G, 512);         // relvec part
    tr(Wt,  WTMT, D, D, G, 768);         // mem part
    tr(Wb,  WBWT, D, 2 * D, 5 * D, 0);   // word part of Wb
    tr(Wb,  WBET, D, D, 5 * D, 512);     // entvec part
    tr(Wb,  WBGT, D, D, 5 * D, 1024);    // target part (feeds M1/c1)
    tr(Wtb, WTBT, D, D, D, 0);
    tr(Wbt, WBTT, D, D, D, 0);

    k_m1<<<D, D, 0, stream>>>(WBGT, Wtt, M1T);
    k_c1<<<1, D, 0, stream>>>(WBGT, btt, C1);
    k_pack8r<<<128, 256, 0, stream>>>(Wb, WREG);
    k_pack8l<<<96, 256, 0, stream>>>(Wb, WLDS);
    k_pack8g<<<32, 256, 0, stream>>>(Wb, WGL);

    k_xg<<<SEQ, 1024, 0, stream>>>(text, wordvector, WihL, bihL, bhhL, XGF);
    k_xg<<<SEQ, 1024, 0, stream>>>(text, wordvector, WihR, bihR, bhhR, XGB);
    k_lstm<<<2, 1024, 0, stream>>>(XGF, XGB, WHLT, WHRT, WORDIN);
    k_prep2<<<SEQ + NREL + NENT, 256, 0, stream>>>(WORDIN, WTWT, WBWT, WTRT, WBET,
                                                   relvec, entvec, bt, bb,
                                                   TW, BW, RVb, EVb);
    k_main7<<<1, 256, 0, stream>>>(TW, BW, RVb, EVb, WTMT, WTBT, WBTT, M1T, C1,
                                   WREG, WLDS, WGL, Wp, bp, Wpl, bpl, btb, bbt,
                                   (float*)d_out);
}